// Round 3
// baseline (5451.850 us; speedup 1.0000x reference)
//
#include <hip/hip_runtime.h>
#include <math.h>

// Multi-kernel graph resonator decoder for MI355X (gfx950).
// Kernel boundaries replace the grid barrier (no fences, no spins, no
// persistent kernel). Per iteration: k_sims (B,K GEMM over D with fp32
// atomics into a double-buffered sims slot) then k_step (exp -> weighted
// phasor superposition -> est update). Softmax Z is skipped entirely:
// atan2 direction is scale-invariant, so unnormalized exp weights are exact.
// Trig table T1[d][{cos,sin}][k] precomputed once (32 MB, L3-resident),
// coalesced along k for BOTH GEMMs.

#define KCODES 1024
#define DIMS   4096
#define BATCH  8
#define NITER_MAX 50   // device-side guard handles *nit_p < NITER_MAX

// ws layout (float offsets). Requires ws >= ~33.1 MB.
#define T1_OFF   0
#define T1_SZ    (DIMS * 2 * KCODES)            // 8,388,608 floats (32 MB)
#define ESTT_OFF (T1_OFF + T1_SZ)
#define ESTT_SZ  (DIMS * BATCH * 2)             // estT[d][b][{c,s}] (256 KB)
#define S_OFF    (ESTT_OFF + ESTT_SZ)
#define S_SZ     (BATCH * KCODES)               // one sims slot (32 KB), x2

// ---- one-time: codebook angles -> T1[d][cs][k] via LDS tile transpose ----
__global__ __launch_bounds__(256) void k_trig(const float* __restrict__ cb,
                                              float* __restrict__ ws) {
  __shared__ float lc[64][65], ls[64][65];
  const int t  = threadIdx.x;
  const int bk = blockIdx.x & 15;        // 16 k-tiles
  const int bd = blockIdx.x >> 4;        // 64 d-tiles
  const int k0 = bk * 64, d0 = bd * 64;
  const int c = t & 63;
  #pragma unroll
  for (int i = 0; i < 16; ++i) {
    const int r = (t >> 6) + i * 4;      // 0..63
    float a = cb[(size_t)(k0 + r) * DIMS + d0 + c];
    float s, cc; sincosf(a, &s, &cc);
    lc[r][c] = cc; ls[r][c] = s;
  }
  __syncthreads();
  float* T1 = ws + T1_OFF;
  #pragma unroll
  for (int j = 0; j < 16; ++j) {
    const int dd = (t >> 6) + j * 4;     // 0..63
    const int kk = c;
    T1[(size_t)((d0 + dd) * 2 + 0) * KCODES + k0 + kk] = lc[kk][dd];
    T1[(size_t)((d0 + dd) * 2 + 1) * KCODES + k0 + kk] = ls[kk][dd];
  }
}

// ---- one-time: est init from superposed ----
__global__ __launch_bounds__(256) void k_init(const float* __restrict__ sup,
                                              float* __restrict__ estT) {
  const int i = blockIdx.x * 256 + threadIdx.x;   // 0..32767
  const int b = i >> 12, d = i & 4095;
  float s, c; sincosf(sup[(size_t)b * DIMS + d], &s, &c);
  estT[d * 16 + b * 2 + 0] = c;
  estT[d * 16 + b * 2 + 1] = s;
}

// ---- per-iter kernel 1: sims[b][k] += sum over this block's 8 dims ----
// 512 blocks x 256 thr; thread = 4 codes (float4) x 8 batches.
__global__ __launch_bounds__(256) void k_sims(float* __restrict__ ws,
                                              const int* __restrict__ nit_p,
                                              int it) {
  if (it > *nit_p) return;               // no-op beyond num_iterations
  const float* T1   = ws + T1_OFF;
  const float* estT = ws + ESTT_OFF;
  float* S = ws + S_OFF + (it & 1) * S_SZ;

  const int t  = threadIdx.x;
  const int d0 = blockIdx.x * 8;         // 8 dims per block
  const int k4 = t * 4;

  float acc[BATCH][4];
  #pragma unroll
  for (int b = 0; b < BATCH; ++b)
    #pragma unroll
    for (int j = 0; j < 4; ++j) acc[b][j] = 0.0f;

  #pragma unroll
  for (int comp = 0; comp < 16; ++comp) {
    const int d = d0 + (comp >> 1), cs = comp & 1;
    const float4 tr = *(const float4*)&T1[(size_t)(d * 2 + cs) * KCODES + k4];
    #pragma unroll
    for (int b = 0; b < BATCH; ++b) {
      // block-uniform contiguous chunk estT[d0*16 .. d0*16+128) -> s_loads
      const float ev = estT[d * 16 + b * 2 + cs];
      acc[b][0] = fmaf(ev, tr.x, acc[b][0]);
      acc[b][1] = fmaf(ev, tr.y, acc[b][1]);
      acc[b][2] = fmaf(ev, tr.z, acc[b][2]);
      acc[b][3] = fmaf(ev, tr.w, acc[b][3]);
    }
  }
  #pragma unroll
  for (int b = 0; b < BATCH; ++b) {
    unsafeAtomicAdd(&S[b * KCODES + k4 + 0], acc[b][0]);
    unsafeAtomicAdd(&S[b * KCODES + k4 + 1], acc[b][1]);
    unsafeAtomicAdd(&S[b * KCODES + k4 + 2], acc[b][2]);
    unsafeAtomicAdd(&S[b * KCODES + k4 + 3], acc[b][3]);
  }
}

// ---- per-iter kernel 2: w = exp(sims*10/4096) (unnormalized);
// re/im[b][d-slice] = sum_k w*trig; est update. Zeroes next sims slot. ----
// 512 blocks x 256 thr; thread OWNS one (k-half, batch, comp) partial:
// 512 serial-k FMAs, no cross-lane reduction.
__global__ __launch_bounds__(256) void k_step(float* __restrict__ ws,
                                              const int* __restrict__ nit_p,
                                              int it) {
  if (it >= *nit_p) return;
  const float* T1 = ws + T1_OFF;
  float* estT  = ws + ESTT_OFF;
  const float* S = ws + S_OFF + (it & 1) * S_SZ;
  float* Snext   = ws + S_OFF + ((it + 1) & 1) * S_SZ;

  __shared__ float wl[BATCH][KCODES + 8];   // pad 8: bank-spread b-stride
  __shared__ float part[256];

  const int t  = threadIdx.x;
  const int d0 = blockIdx.x * 8;
  const float c2 = 0.00244140625f * 1.4426950408889634f;  // (10/4096)*log2(e)

  // unnormalized weights -> LDS (Z cancels in atan2 direction)
  #pragma unroll
  for (int b = 0; b < BATCH; ++b) {
    const float4 s4 = *(const float4*)&S[b * KCODES + 4 * t];
    wl[b][4 * t + 0] = exp2f(s4.x * c2);
    wl[b][4 * t + 1] = exp2f(s4.y * c2);
    wl[b][4 * t + 2] = exp2f(s4.z * c2);
    wl[b][4 * t + 3] = exp2f(s4.w * c2);
  }
  __syncthreads();

  // thread -> (half, b, comp)
  const int half = t >> 7, b = (t >> 4) & 7, comp = t & 15;
  const int d = d0 + (comp >> 1), cs = comp & 1;
  const float* trow = &T1[(size_t)(d * 2 + cs) * KCODES + half * 512];
  const float* wrow = &wl[b][half * 512];
  float a0 = 0.f, a1 = 0.f, a2 = 0.f, a3 = 0.f;
  #pragma unroll 8
  for (int k = 0; k < 512; k += 4) {
    const float4 tv = *(const float4*)&trow[k];
    const float4 wv = *(const float4*)&wrow[k];
    a0 = fmaf(wv.x, tv.x, a0);
    a1 = fmaf(wv.y, tv.y, a1);
    a2 = fmaf(wv.z, tv.z, a2);
    a3 = fmaf(wv.w, tv.w, a3);
  }
  part[t] = (a0 + a1) + (a2 + a3);
  __syncthreads();

  if (t < 128) part[t] += part[t + 128];   // combine k-halves
  __syncthreads();

  if (t < 64) {                            // finalize 8 dims x 8 batches
    const int bb = t >> 3, dd = t & 7;
    const float re = part[bb * 16 + dd * 2 + 0];
    const float im = part[bb * 16 + dd * 2 + 1];
    const float n2 = fmaf(re, re, im * im);
    float ec, es;
    if (n2 > 0.0f) {
      const float inv = rsqrtf(n2);
      ec = re * inv; es = im * inv;
    } else { ec = 1.0f; es = 0.0f; }       // atan2(0,0)=0
    estT[(d0 + dd) * 16 + bb * 2 + 0] = ec;
    estT[(d0 + dd) * 16 + bb * 2 + 1] = es;
  }
  if (t < 16) Snext[blockIdx.x * 16 + t] = 0.0f;  // zero next slot, distributed
}

// ---- epilogue: out = final raw sims / DIMS ----
__global__ __launch_bounds__(256) void k_out(const float* __restrict__ ws,
                                             const int* __restrict__ nit_p,
                                             float* __restrict__ out) {
  const int i = blockIdx.x * 256 + threadIdx.x;   // 0..8191
  const float* S = ws + S_OFF + ((*nit_p) & 1) * S_SZ;
  out[i] = S[i] * (1.0f / (float)DIMS);
}

extern "C" void kernel_launch(void* const* d_in, const int* in_sizes, int n_in,
                              void* d_out, int out_size, void* d_ws, size_t ws_size,
                              hipStream_t stream) {
  const float* sup = (const float*)d_in[0];
  const float* cbk = (const float*)d_in[1];
  const int*   nit = (const int*)d_in[2];
  float* outp = (float*)d_out;
  float* ws   = (float*)d_ws;

  // zero sims slot 0 (slot 1 is zeroed by k_step(0)); graph-capture safe
  hipMemsetAsync((void*)(ws + S_OFF), 0, S_SZ * sizeof(float), stream);

  hipLaunchKernelGGL(k_trig, dim3(1024), dim3(256), 0, stream, cbk, ws);
  hipLaunchKernelGGL(k_init, dim3(128),  dim3(256), 0, stream, sup, ws + ESTT_OFF);

  for (int it = 0; it < NITER_MAX; ++it) {
    hipLaunchKernelGGL(k_sims, dim3(512), dim3(256), 0, stream, ws, nit, it);
    hipLaunchKernelGGL(k_step, dim3(512), dim3(256), 0, stream, ws, nit, it);
  }
  hipLaunchKernelGGL(k_sims, dim3(512), dim3(256), 0, stream, ws, nit, NITER_MAX);
  hipLaunchKernelGGL(k_out,  dim3(32),  dim3(256), 0, stream, ws, nit, outp);
}

// Round 4
// 1093.438 us; speedup vs baseline: 4.9860x; 4.9860x over previous
//
#include <hip/hip_runtime.h>
#include <math.h>

// Atomic-free multi-kernel resonator decoder for MI355X (gfx950).
// Per iteration: k_sims (partial sims, block-local reduce, plain stores) ->
// k_wexp (reduce 16 partials + unnormalized exp) -> k_step (w.T1 GEMM with
// w in registers, DPP wave reduction, fused est normalize).
// Softmax Z skipped (atan2 direction is scale-invariant). No trig in loop
// (cos(atan2(im,re)) = re/|z|). Trig table T1[row=d*2+cs][k] built once
// (32 MB, L3-resident), k-contiguous => coalesced in BOTH GEMM kernels.

#define KCODES 1024
#define DIMS   4096
#define BATCH  8
#define NITER_MAX 50       // device-side guard handles *nit_p < NITER_MAX
#define DSPLIT 16

// ws layout (float offsets); total ~34.4 MB.
#define T1_OFF  0
#define T1_SZ   (DIMS * 2 * KCODES)            // 8,388,608
#define EST_OFF (T1_OFF + T1_SZ)
#define EST_SZ  (DIMS * 2 * BATCH)             // est[row=d*2+cs][b], 65,536
#define P_OFF   (EST_OFF + EST_SZ)
#define P_SZ    (DSPLIT * BATCH * KCODES)      // partials [ds][b][k], 131,072
#define W_OFF   (P_OFF + P_SZ)
#define W_SZ    (BATCH * KCODES)               // weights [b][k], 8,192

// ---- DPP wave64 sum: result valid in lane 63 ----
template <int CTRL>
__device__ __forceinline__ float dpp_add(float x) {
  int v = __builtin_amdgcn_update_dpp(0, __float_as_int(x), CTRL, 0xF, 0xF, false);
  return x + __int_as_float(v);
}
__device__ __forceinline__ float wave_sum64(float x) {
  x = dpp_add<0x111>(x);   // row_shr:1
  x = dpp_add<0x112>(x);   // row_shr:2
  x = dpp_add<0x114>(x);   // row_shr:4
  x = dpp_add<0x118>(x);   // row_shr:8
  x = dpp_add<0x142>(x);   // row_bcast:15
  x = dpp_add<0x143>(x);   // row_bcast:31
  return x;                // lane 63 = sum of all 64 lanes
}

// ---- one-time: codebook angles -> T1[(d*2+cs)][k] via LDS tile transpose ----
__global__ __launch_bounds__(256) void k_trig(const float* __restrict__ cb,
                                              float* __restrict__ ws) {
  __shared__ float lc[64][65], ls[64][65];
  const int t  = threadIdx.x;
  const int bk = blockIdx.x & 15;        // 16 k-tiles
  const int bd = blockIdx.x >> 4;        // 64 d-tiles
  const int k0 = bk * 64, d0 = bd * 64;
  const int c = t & 63;
  #pragma unroll
  for (int i = 0; i < 16; ++i) {
    const int r = (t >> 6) + i * 4;      // 0..63
    float a = cb[(size_t)(k0 + r) * DIMS + d0 + c];
    float s, cc; sincosf(a, &s, &cc);
    lc[r][c] = cc; ls[r][c] = s;
  }
  __syncthreads();
  float* T1 = ws + T1_OFF;
  #pragma unroll
  for (int j = 0; j < 16; ++j) {
    const int dd = (t >> 6) + j * 4;     // 0..63
    const int kk = c;
    T1[(size_t)((d0 + dd) * 2 + 0) * KCODES + k0 + kk] = lc[kk][dd];
    T1[(size_t)((d0 + dd) * 2 + 1) * KCODES + k0 + kk] = ls[kk][dd];
  }
}

// ---- one-time: est init from superposed ----
__global__ __launch_bounds__(256) void k_init(const float* __restrict__ sup,
                                              float* __restrict__ ws) {
  float* EST = ws + EST_OFF;
  const int i = blockIdx.x * 256 + threadIdx.x;   // 0..32767
  const int b = i >> 12, d = i & 4095;
  float s, c; sincosf(sup[(size_t)b * DIMS + d], &s, &c);
  EST[(d * 2 + 0) * BATCH + b] = c;
  EST[(d * 2 + 1) * BATCH + b] = s;
}

// ---- per-iter 1: partial sims. Block = (512 rows) x (64 k). No atomics. ----
__global__ __launch_bounds__(256) void k_sims(float* __restrict__ ws,
                                              const int* __restrict__ nit_p,
                                              int it) {
  if (it > *nit_p) return;               // it == NI is the final sims pass
  const float* T1  = ws + T1_OFF;
  const float* EST = ws + EST_OFF;
  float* P = ws + P_OFF;

  const int t  = threadIdx.x;
  const int ds = blockIdx.x >> 4;        // 0..15 d-split
  const int ks = blockIdx.x & 15;        // 0..15 k-split
  const int r0 = ds * 512;               // 512 rows of T1 (256 dims x 2 cs)
  const int k0 = ks * 64;
  const int dg = t >> 4;                 // 0..15 row-group
  const int kl = t & 15;                 // 0..15 k-lane (float4)
  const int kk = k0 + kl * 4;

  float4 acc[BATCH];
  #pragma unroll
  for (int b = 0; b < BATCH; ++b) acc[b] = make_float4(0.f, 0.f, 0.f, 0.f);

  #pragma unroll 8
  for (int rr = 0; rr < 32; ++rr) {
    const int row = r0 + dg * 32 + rr;
    const float4 tv = *(const float4*)&T1[(size_t)row * KCODES + kk];
    const float4 e0 = *(const float4*)&EST[row * BATCH + 0];
    const float4 e1 = *(const float4*)&EST[row * BATCH + 4];
    const float ev[8] = {e0.x, e0.y, e0.z, e0.w, e1.x, e1.y, e1.z, e1.w};
    #pragma unroll
    for (int b = 0; b < BATCH; ++b) {
      acc[b].x = fmaf(ev[b], tv.x, acc[b].x);
      acc[b].y = fmaf(ev[b], tv.y, acc[b].y);
      acc[b].z = fmaf(ev[b], tv.z, acc[b].z);
      acc[b].w = fmaf(ev[b], tv.w, acc[b].w);
    }
  }

  // in-block reduce over the 16 row-groups
  __shared__ float4 red[16][BATCH][16];  // [dg][b][kl] = 32 KB
  #pragma unroll
  for (int b = 0; b < BATCH; ++b) red[dg][b][kl] = acc[b];
  __syncthreads();

  // thread sums one float2 of output (2 of 512 block outputs)
  const int b2  = t >> 5;                // 0..7
  const int klc = (2 * t) & 63;          // even 0..62
  const int kl2 = klc >> 2, j0 = klc & 3;
  float2 s = make_float2(0.f, 0.f);
  #pragma unroll
  for (int g = 0; g < 16; ++g) {
    const float2 v = *(const float2*)((const float*)&red[g][b2][kl2] + j0);
    s.x += v.x; s.y += v.y;
  }
  *(float2*)&P[ds * (BATCH * KCODES) + b2 * KCODES + k0 + klc] = s;
}

// ---- per-iter 2: w = exp2(c2 * sum of 16 partials) (unnormalized) ----
__global__ __launch_bounds__(256) void k_wexp(float* __restrict__ ws,
                                              const int* __restrict__ nit_p,
                                              int it) {
  if (it >= *nit_p) return;
  const float* P = ws + P_OFF;
  float* W = ws + W_OFF;
  const int i4 = (blockIdx.x * 256 + threadIdx.x) * 4;   // 0..8188
  float4 s = make_float4(0.f, 0.f, 0.f, 0.f);
  #pragma unroll
  for (int g = 0; g < DSPLIT; ++g) {
    const float4 v = *(const float4*)&P[g * (BATCH * KCODES) + i4];
    s.x += v.x; s.y += v.y; s.z += v.z; s.w += v.w;
  }
  const float c2 = 0.00244140625f * 1.4426950408889634f; // (10/4096)*log2(e)
  float4 w;
  w.x = exp2f(s.x * c2); w.y = exp2f(s.y * c2);
  w.z = exp2f(s.z * c2); w.w = exp2f(s.w * c2);
  *(float4*)&W[i4] = w;
}

// ---- per-iter 3: re/im = w . T1 rows; est normalize. Block = 32 rows. ----
__global__ __launch_bounds__(256) void k_step(float* __restrict__ ws,
                                              const int* __restrict__ nit_p,
                                              int it) {
  if (it >= *nit_p) return;
  const float* T1 = ws + T1_OFF;
  float* EST = ws + EST_OFF;
  const float* W = ws + W_OFF;

  __shared__ float wl[BATCH * KCODES];   // 32 KB
  __shared__ float red2[32 * BATCH];     // [row_local][b]

  const int t = threadIdx.x;
  #pragma unroll
  for (int j = 0; j < 8; ++j)
    *(float4*)&wl[(j * 256 + t) * 4] = *(const float4*)&W[(j * 256 + t) * 4];
  __syncthreads();

  const int wave = t >> 6, lane = t & 63;
  const int r0 = blockIdx.x * 32 + wave * 8;

  float acc[8][BATCH];
  #pragma unroll
  for (int r = 0; r < 8; ++r)
    #pragma unroll
    for (int b = 0; b < BATCH; ++b) acc[r][b] = 0.f;

  #pragma unroll
  for (int c = 0; c < 4; ++c) {
    const int kk = c * 256 + lane * 4;
    float4 wr[BATCH];
    #pragma unroll
    for (int b = 0; b < BATCH; ++b)
      wr[b] = *(const float4*)&wl[b * KCODES + kk];
    #pragma unroll
    for (int r = 0; r < 8; ++r) {
      const float4 tv = *(const float4*)&T1[(size_t)(r0 + r) * KCODES + kk];
      #pragma unroll
      for (int b = 0; b < BATCH; ++b) {
        acc[r][b] = fmaf(wr[b].x, tv.x, acc[r][b]);
        acc[r][b] = fmaf(wr[b].y, tv.y, acc[r][b]);
        acc[r][b] = fmaf(wr[b].z, tv.z, acc[r][b]);
        acc[r][b] = fmaf(wr[b].w, tv.w, acc[r][b]);
      }
    }
  }

  #pragma unroll
  for (int r = 0; r < 8; ++r)
    #pragma unroll
    for (int b = 0; b < BATCH; ++b) {
      const float s = wave_sum64(acc[r][b]);
      if (lane == 63) red2[(wave * 8 + r) * BATCH + b] = s;
    }
  __syncthreads();

  if (t < 128) {                         // 16 dims x 8 batches
    const int b = t & 7, dl = t >> 3;
    const float re = red2[(dl * 2 + 0) * BATCH + b];
    const float im = red2[(dl * 2 + 1) * BATCH + b];
    const float n2 = fmaf(re, re, im * im);
    float ec, es;
    if (n2 > 0.f) {
      const float inv = rsqrtf(n2);
      ec = re * inv; es = im * inv;
    } else { ec = 1.f; es = 0.f; }       // atan2(0,0) = 0
    EST[(blockIdx.x * 32 + dl * 2 + 0) * BATCH + b] = ec;
    EST[(blockIdx.x * 32 + dl * 2 + 1) * BATCH + b] = es;
  }
}

// ---- epilogue: out = (sum of 16 partials) / DIMS ----
__global__ __launch_bounds__(256) void k_out(const float* __restrict__ ws,
                                             float* __restrict__ out) {
  const float* P = ws + P_OFF;
  const int i4 = (blockIdx.x * 256 + threadIdx.x) * 4;
  float4 s = make_float4(0.f, 0.f, 0.f, 0.f);
  #pragma unroll
  for (int g = 0; g < DSPLIT; ++g) {
    const float4 v = *(const float4*)&P[g * (BATCH * KCODES) + i4];
    s.x += v.x; s.y += v.y; s.z += v.z; s.w += v.w;
  }
  const float sc = 1.0f / (float)DIMS;
  float4 o; o.x = s.x * sc; o.y = s.y * sc; o.z = s.z * sc; o.w = s.w * sc;
  *(float4*)&out[i4] = o;
}

extern "C" void kernel_launch(void* const* d_in, const int* in_sizes, int n_in,
                              void* d_out, int out_size, void* d_ws, size_t ws_size,
                              hipStream_t stream) {
  const float* sup = (const float*)d_in[0];
  const float* cbk = (const float*)d_in[1];
  const int*   nit = (const int*)d_in[2];
  float* outp = (float*)d_out;
  float* ws   = (float*)d_ws;

  hipLaunchKernelGGL(k_trig, dim3(1024), dim3(256), 0, stream, cbk, ws);
  hipLaunchKernelGGL(k_init, dim3(128),  dim3(256), 0, stream, sup, ws);

  for (int it = 0; it < NITER_MAX; ++it) {
    hipLaunchKernelGGL(k_sims, dim3(256), dim3(256), 0, stream, ws, nit, it);
    hipLaunchKernelGGL(k_wexp, dim3(8),   dim3(256), 0, stream, ws, nit, it);
    hipLaunchKernelGGL(k_step, dim3(256), dim3(256), 0, stream, ws, nit, it);
  }
  hipLaunchKernelGGL(k_sims, dim3(256), dim3(256), 0, stream, ws, nit, NITER_MAX);
  hipLaunchKernelGGL(k_out,  dim3(8),   dim3(256), 0, stream, ws, outp);
}